// Round 1
// baseline (714.865 us; speedup 1.0000x reference)
//
#include <hip/hip_runtime.h>
#include <hip/hip_bf16.h>

// Problem constants
#define BB 16
#define NN 512
#define DD 256
#define HH 8
#define DK 32
#define CC 16

__device__ __forceinline__ float gelu_f(float x) {
    return 0.5f * x * (1.0f + erff(x * 0.70710678118654752f));
}

// ---------------------------------------------------------------------------
// Batched GEMM: C[b] = act( A[b] @ W + bias + bias2[b] )
// A: [B, M, K] (optionally gelu applied on load), W: [K, N] shared,
// bias: [N] or null, bias2: [B, N] or null. M=512 (or 512), K=256, N=256.
// Tile 64x64, BK=16, 256 threads, 4x4 micro-tile per thread.
// ---------------------------------------------------------------------------
template<int AGELU, int ACT>
__global__ __launch_bounds__(256) void gemm_ba(
    const float* __restrict__ A, const float* __restrict__ W,
    float* __restrict__ C, const float* __restrict__ bias,
    const float* __restrict__ bias2, int M, int Kd, int Nd)
{
    __shared__ float As[16][65];   // [k][m], padded
    __shared__ float Bs[16][68];   // [k][n], padded (float4-friendly)

    const int tid = threadIdx.x;
    const int tx = tid & 15, ty = tid >> 4;
    const int bx = blockIdx.x * 64, by = blockIdx.y * 64;
    const size_t bofs = (size_t)blockIdx.z * M * Kd;
    const float* Ab = A + bofs;
    float* Cb = C + (size_t)blockIdx.z * M * Nd;

    const int am = tid >> 2;          // 0..63 (row within tile)
    const int ak = (tid & 3) << 2;    // 0,4,8,12
    const int bk = tid >> 4;          // 0..15
    const int bn = (tid & 15) << 2;   // 0..60

    float acc[4][4] = {};

    for (int k0 = 0; k0 < Kd; k0 += 16) {
        // load A tile (64 x 16)
        float4 av = *(const float4*)(Ab + (size_t)(by + am) * Kd + k0 + ak);
        if (AGELU) {
            av.x = gelu_f(av.x); av.y = gelu_f(av.y);
            av.z = gelu_f(av.z); av.w = gelu_f(av.w);
        }
        As[ak + 0][am] = av.x; As[ak + 1][am] = av.y;
        As[ak + 2][am] = av.z; As[ak + 3][am] = av.w;
        // load B tile (16 x 64)
        float4 bv = *(const float4*)(W + (size_t)(k0 + bk) * Nd + bx + bn);
        Bs[bk][bn + 0] = bv.x; Bs[bk][bn + 1] = bv.y;
        Bs[bk][bn + 2] = bv.z; Bs[bk][bn + 3] = bv.w;
        __syncthreads();
#pragma unroll
        for (int k = 0; k < 16; ++k) {
            float a[4], bb[4];
#pragma unroll
            for (int i = 0; i < 4; ++i) a[i] = As[k][(ty << 2) + i];
#pragma unroll
            for (int j = 0; j < 4; ++j) bb[j] = Bs[k][(tx << 2) + j];
#pragma unroll
            for (int i = 0; i < 4; ++i)
#pragma unroll
                for (int j = 0; j < 4; ++j)
                    acc[i][j] += a[i] * bb[j];
        }
        __syncthreads();
    }

    const int row = by + (ty << 2), col = bx + (tx << 2);
#pragma unroll
    for (int i = 0; i < 4; ++i) {
#pragma unroll
        for (int j = 0; j < 4; ++j) {
            float v = acc[i][j];
            if (bias)  v += bias[col + j];
            if (bias2) v += bias2[blockIdx.z * Nd + col + j];
            if (ACT)   v = gelu_f(v);
            Cb[(size_t)(row + i) * Nd + col + j] = v;
        }
    }
}

// ---------------------------------------------------------------------------
// Attention: O[n,h,:] = softmax(Q[n,h,:]·K[:,h,:]^T / sqrt(DK)) @ V[:,h,:]
// Q,K,V,O: [B, N, D] with head-major columns (h*DK+d).
// Block: 256 threads = 4 waves, 2 query rows per wave -> 8 rows/block.
// Grid: (N/8, H, B). K/V tiles staged in LDS (64 keys x 32 dims, pad 33).
// ---------------------------------------------------------------------------
__global__ __launch_bounds__(256) void attn_kernel(
    const float* __restrict__ Q, const float* __restrict__ K,
    const float* __restrict__ V, float* __restrict__ O)
{
    const int b = blockIdx.z, h = blockIdx.y;
    const int wave = threadIdx.x >> 6, lane = threadIdx.x & 63;
    const int n0 = blockIdx.x * 8;

    __shared__ float qs[8][32];
    __shared__ float ps[8][512];
    __shared__ float tile[64][33];

    const size_t bh = (size_t)b * NN * DD + h * DK;
    const float* Kb = K + bh;
    const float* Vb = V + bh;

    {
        int r = threadIdx.x >> 5, d = threadIdx.x & 31;
        qs[r][d] = Q[((size_t)b * NN + n0 + r) * DD + h * DK + d] * 0.17677669529663689f;
    }
    __syncthreads();

    float sv[2][8];
    float smax[2] = {-1e30f, -1e30f};

    for (int kb = 0; kb < 8; ++kb) {
        // cooperative K tile load: 64 keys x 32 dims
#pragma unroll
        for (int r = 0; r < 2; ++r) {
            int linear = threadIdx.x + r * 256;      // float4 index
            int j = linear >> 3, dq = (linear & 7) << 2;
            const float4 kv = *(const float4*)(Kb + (size_t)(kb * 64 + j) * DD + dq);
            tile[j][dq + 0] = kv.x; tile[j][dq + 1] = kv.y;
            tile[j][dq + 2] = kv.z; tile[j][dq + 3] = kv.w;
        }
        __syncthreads();
#pragma unroll
        for (int rr = 0; rr < 2; ++rr) {
            int row = wave * 2 + rr;
            float s = 0.f;
#pragma unroll
            for (int d = 0; d < 32; ++d) s += qs[row][d] * tile[lane][d];
            sv[rr][kb] = s;
            smax[rr] = fmaxf(smax[rr], s);
        }
        __syncthreads();
    }

    float inv[2];
#pragma unroll
    for (int rr = 0; rr < 2; ++rr) {
        int row = wave * 2 + rr;
        float m = smax[rr];
        for (int off = 32; off; off >>= 1) m = fmaxf(m, __shfl_xor(m, off, 64));
        float lsum = 0.f;
#pragma unroll
        for (int kb = 0; kb < 8; ++kb) {
            float p = __expf(sv[rr][kb] - m);
            ps[row][kb * 64 + lane] = p;
            lsum += p;
        }
        for (int off = 32; off; off >>= 1) lsum += __shfl_xor(lsum, off, 64);
        inv[rr] = 1.0f / lsum;
    }

    float acc[2] = {0.f, 0.f};
    const int d = lane & 31, half = lane >> 5;

    for (int kb = 0; kb < 8; ++kb) {
        __syncthreads();   // prior tile reads done before overwrite
#pragma unroll
        for (int r = 0; r < 2; ++r) {
            int linear = threadIdx.x + r * 256;
            int j = linear >> 3, dq = (linear & 7) << 2;
            const float4 vv = *(const float4*)(Vb + (size_t)(kb * 64 + j) * DD + dq);
            tile[j][dq + 0] = vv.x; tile[j][dq + 1] = vv.y;
            tile[j][dq + 2] = vv.z; tile[j][dq + 3] = vv.w;
        }
        __syncthreads();
#pragma unroll
        for (int rr = 0; rr < 2; ++rr) {
            int row = wave * 2 + rr;
#pragma unroll
            for (int jj = 0; jj < 32; ++jj) {
                int j = half * 32 + jj;
                acc[rr] += ps[row][kb * 64 + j] * tile[j][d];
            }
        }
    }

#pragma unroll
    for (int rr = 0; rr < 2; ++rr) {
        float a = acc[rr] + __shfl_xor(acc[rr], 32, 64);
        int row = wave * 2 + rr;
        if (lane < 32)
            O[((size_t)b * NN + n0 + row) * DD + h * DK + d] = a * inv[rr];
    }
}

// ---------------------------------------------------------------------------
// Per-episode: aggr = gelu(mean_n X[n,:]); aggr2 = aggr@res_W + res_b;
// tvec[o] = sum_k gelu(aggr2[k]) * W1[k,o]   (top half of ff_W1)
// Grid: B, block 256 (one thread per d).
// ---------------------------------------------------------------------------
__global__ __launch_bounds__(256) void aggr_kernel(
    const float* __restrict__ X, const float* __restrict__ resW,
    const float* __restrict__ resb, const float* __restrict__ W1,
    float* __restrict__ tvec)
{
    const int b = blockIdx.x, d = threadIdx.x;
    const float* Xb = X + (size_t)b * NN * DD;
    __shared__ float a[256], a2[256];

    float s = 0.f;
    for (int n = 0; n < NN; ++n) s += Xb[(size_t)n * DD + d];
    a[d] = gelu_f(s * (1.0f / NN));
    __syncthreads();

    float t = resb[d];
    for (int k = 0; k < 256; ++k) t += a[k] * resW[(size_t)k * 256 + d];
    a2[d] = gelu_f(t);
    __syncthreads();

    float u = 0.f;
    for (int k = 0; k < 256; ++k) u += a2[k] * W1[(size_t)k * 256 + d];
    tvec[b * 256 + d] = u;
}

// ---------------------------------------------------------------------------
// Class sums: g[b,c,:] = sum_{n: label=c} F[b,n,:], counts[b,c]
// Grid: B, block 256.
// ---------------------------------------------------------------------------
__global__ __launch_bounds__(256) void classsum_kernel(
    const float* __restrict__ F, const int* __restrict__ labels,
    float* __restrict__ g, float* __restrict__ counts)
{
    const int b = blockIdx.x, d = threadIdx.x;
    __shared__ int lab[NN];
    __shared__ float gs[CC][256];

    for (int i = d; i < NN; i += 256) lab[i] = labels[b * NN + i];
#pragma unroll
    for (int c = 0; c < CC; ++c) gs[c][d] = 0.f;
    __syncthreads();

    const float* Fb = F + (size_t)b * NN * DD;
    for (int n = 0; n < NN; ++n) gs[lab[n]][d] += Fb[(size_t)n * DD + d];
    __syncthreads();

#pragma unroll
    for (int c = 0; c < CC; ++c)
        g[((size_t)b * CC + c) * 256 + d] = gs[c][d];
    if (d < CC) {
        int cnt = 0;
        for (int n = 0; n < NN; ++n) cnt += (lab[n] == d);
        counts[b * CC + d] = (float)cnt;
    }
}

// ---------------------------------------------------------------------------
// Output: out[b,n,c] = (f_n·g[c] - [lab_n==c]*||f_n||^2) / (counts[c]-[lab_n==c])
// Grid: (N/4, B), block 256 = 4 waves, one row per wave.
// ---------------------------------------------------------------------------
__global__ __launch_bounds__(256) void out_kernel(
    const float* __restrict__ F, const int* __restrict__ labels,
    const float* __restrict__ g, const float* __restrict__ counts,
    float* __restrict__ out)
{
    const int b = blockIdx.y;
    const int wave = threadIdx.x >> 6, lane = threadIdx.x & 63;
    const int n = blockIdx.x * 4 + wave;

    const float* fn = F + ((size_t)b * NN + n) * DD;
    const float* gb = g + (size_t)b * CC * 256;

    float fv[4];
#pragma unroll
    for (int i = 0; i < 4; ++i) fv[i] = fn[lane * 4 + i];

    float selfdot = 0.f;
#pragma unroll
    for (int i = 0; i < 4; ++i) selfdot += fv[i] * fv[i];

    float accs[CC];
#pragma unroll
    for (int c = 0; c < CC; ++c) {
        float s = 0.f;
#pragma unroll
        for (int i = 0; i < 4; ++i) s += fv[i] * gb[c * 256 + lane * 4 + i];
        accs[c] = s;
    }
    for (int off = 32; off; off >>= 1) {
        selfdot += __shfl_xor(selfdot, off, 64);
#pragma unroll
        for (int c = 0; c < CC; ++c) accs[c] += __shfl_xor(accs[c], off, 64);
    }

    if (lane < CC) {
        const int c = lane;
        const int same = (labels[b * NN + n] == c) ? 1 : 0;
        float num = accs[c] - (same ? selfdot : 0.f);
        float den = counts[b * CC + c] - (float)same;
        out[((size_t)b * NN + n) * CC + c] = num / den;
    }
}

// ---------------------------------------------------------------------------
extern "C" void kernel_launch(void* const* d_in, const int* in_sizes, int n_in,
                              void* d_out, int out_size, void* d_ws, size_t ws_size,
                              hipStream_t stream)
{
    const float* emb   = (const float*)d_in[0];
    const int*   labels= (const int*)  d_in[1];
    const float* Wq0   = (const float*)d_in[2];
    const float* Wk0   = (const float*)d_in[3];
    const float* Wv0   = (const float*)d_in[4];
    const float* Wo0   = (const float*)d_in[5];
    const float* Wq1   = (const float*)d_in[6];
    const float* Wk1   = (const float*)d_in[7];
    const float* Wv1   = (const float*)d_in[8];
    const float* Wo1   = (const float*)d_in[9];
    const float* resW  = (const float*)d_in[10];
    const float* resb  = (const float*)d_in[11];
    const float* ffW1  = (const float*)d_in[12];
    const float* ffb1  = (const float*)d_in[13];
    const float* ffW2  = (const float*)d_in[14];
    const float* ffb2  = (const float*)d_in[15];
    float* out = (float*)d_out;

    float* ws = (float*)d_ws;
    const size_t SB = (size_t)BB * NN * DD;   // 2,097,152 floats
    float* Q      = ws;
    float* Kbuf   = ws + SB;
    float* Vbuf   = ws + 2 * SB;
    float* T0     = ws + 3 * SB;
    float* T1     = ws + 4 * SB;
    float* tvec   = ws + 5 * SB;              // [B,256]
    float* gsum   = tvec + BB * 256;          // [B,C,256]
    float* counts = gsum + BB * CC * 256;     // [B,C]

    const dim3 gg(4, 8, BB);        // N=256 tiles x, M=512 tiles y
    const dim3 ga(64, HH, BB);      // attention

    // layer 0 projections
    gemm_ba<0,0><<<gg, 256, 0, stream>>>(emb, Wq0, Q,    nullptr, nullptr, NN, DD, DD);
    gemm_ba<0,0><<<gg, 256, 0, stream>>>(emb, Wk0, Kbuf, nullptr, nullptr, NN, DD, DD);
    gemm_ba<0,0><<<gg, 256, 0, stream>>>(emb, Wv0, Vbuf, nullptr, nullptr, NN, DD, DD);
    attn_kernel<<<ga, 256, 0, stream>>>(Q, Kbuf, Vbuf, T0);
    // x1 = gelu(attn0 @ Wo0)
    gemm_ba<0,1><<<gg, 256, 0, stream>>>(T0, Wo0, T1, nullptr, nullptr, NN, DD, DD);
    // layer 1 projections
    gemm_ba<0,0><<<gg, 256, 0, stream>>>(T1, Wq1, Q,    nullptr, nullptr, NN, DD, DD);
    gemm_ba<0,0><<<gg, 256, 0, stream>>>(T1, Wk1, Kbuf, nullptr, nullptr, NN, DD, DD);
    gemm_ba<0,0><<<gg, 256, 0, stream>>>(T1, Wv1, Vbuf, nullptr, nullptr, NN, DD, DD);
    attn_kernel<<<ga, 256, 0, stream>>>(Q, Kbuf, Vbuf, T0);
    // x2 = attn1 @ Wo1
    gemm_ba<0,0><<<gg, 256, 0, stream>>>(T0, Wo1, T1, nullptr, nullptr, NN, DD, DD);
    // aggr path -> tvec
    aggr_kernel<<<BB, 256, 0, stream>>>(T1, resW, resb, ffW1, tvec);
    // h = gelu( gelu(e) @ W1[256:512,:] + tvec + b1 )
    gemm_ba<1,1><<<gg, 256, 0, stream>>>(emb, ffW1 + 256 * 256, T0, ffb1, tvec, NN, DD, DD);
    // f = h @ W2 + b2
    gemm_ba<0,0><<<gg, 256, 0, stream>>>(T0, ffW2, T1, ffb2, nullptr, NN, DD, DD);
    // class sums + output
    classsum_kernel<<<BB, 256, 0, stream>>>(T1, labels, gsum, counts);
    out_kernel<<<dim3(128, BB), 256, 0, stream>>>(T1, labels, gsum, counts, out);
}

// Round 2
// 351.253 us; speedup vs baseline: 2.0352x; 2.0352x over previous
//
#include <hip/hip_runtime.h>

#define BB 16
#define NN 512
#define DD 256
#define HH 8
#define CC 16

typedef unsigned short u16;
using short8 = __attribute__((ext_vector_type(8))) short;
using f32x4  = __attribute__((ext_vector_type(4))) float;

__device__ __forceinline__ float gelu_f(float x) {
    return 0.5f * x * (1.0f + erff(x * 0.70710678118654752f));
}
__device__ __forceinline__ u16 f2bf(float f) {
    unsigned int u = __float_as_uint(f);
    unsigned int r = u + 0x7FFFu + ((u >> 16) & 1u);
    return (u16)(r >> 16);
}
__device__ __forceinline__ float bf2f(u16 h) {
    return __uint_as_float(((unsigned int)h) << 16);
}
// async global->LDS, 16B per lane; LDS dest is wave-uniform base + lane*16
__device__ __forceinline__ void gld16(const u16* g, const u16* l) {
    __builtin_amdgcn_global_load_lds(
        (const __attribute__((address_space(1))) unsigned int*)g,
        (__attribute__((address_space(3))) unsigned int*)l, 16, 0, 0);
}

// ---------------------------------------------------------------------------
// bf16 MFMA GEMM: O = act(A @ W^T' + bias + tvec[ep]); A: [8192 x 256] bf16,
// W*: [256 n x 256 k] bf16 (pre-transposed), 128x128 tile, BK=32, 4 waves.
// grid.x = 64 m-tiles, grid.y = 2*nW (sel = y>>1 picks W/O, y&1 picks n-half).
// ---------------------------------------------------------------------------
template<int ACT, int HAS_B, int HAS_T, int OUT_F32>
__global__ __launch_bounds__(256) void gemm_bf16(
    const u16* __restrict__ A,
    const u16* __restrict__ W0, const u16* __restrict__ W1, const u16* __restrict__ W2,
    u16* __restrict__ O0, u16* __restrict__ O1, u16* __restrict__ O2,
    float* __restrict__ OF,
    const float* __restrict__ bias, const float* __restrict__ tvec)
{
    __shared__ __align__(16) u16 As[128 * 32];
    __shared__ __align__(16) u16 Bs[128 * 32];
    const int tid = threadIdx.x, wave = tid >> 6, lane = tid & 63;
    const int col = lane & 15, quad = lane >> 4;
    const int mbase = blockIdx.x * 128;
    const int sel = blockIdx.y >> 1;
    const int nbase = (blockIdx.y & 1) * 128;
    const u16* W = (sel == 0) ? W0 : ((sel == 1) ? W1 : W2);
    u16* O = (sel == 0) ? O0 : ((sel == 1) ? O1 : O2);

    const int srow = lane >> 2;        // 0..15
    const int skk  = (lane & 3) * 8;   // 0,8,16,24

    f32x4 acc[4][4];
#pragma unroll
    for (int i = 0; i < 4; ++i)
#pragma unroll
        for (int j = 0; j < 4; ++j) acc[i][j] = (f32x4){0.f, 0.f, 0.f, 0.f};

    const int m0 = (wave & 1) * 64, n0 = (wave >> 1) * 64;

    for (int k0 = 0; k0 < DD; k0 += 32) {
#pragma unroll
        for (int c = 0; c < 2; ++c) {
            const int ch = wave * 2 + c;
            const int row = ch * 16 + srow;
            gld16(A + (size_t)(mbase + row) * DD + k0 + skk, &As[ch * 512]);
            gld16(W + (size_t)(nbase + row) * DD + k0 + skk, &Bs[ch * 512]);
        }
        __syncthreads();
        short8 af[4], bfr[4];
#pragma unroll
        for (int i = 0; i < 4; ++i) af[i]  = *(const short8*)&As[(m0 + i * 16 + col) * 32 + quad * 8];
#pragma unroll
        for (int j = 0; j < 4; ++j) bfr[j] = *(const short8*)&Bs[(n0 + j * 16 + col) * 32 + quad * 8];
#pragma unroll
        for (int i = 0; i < 4; ++i)
#pragma unroll
            for (int j = 0; j < 4; ++j)
                acc[i][j] = __builtin_amdgcn_mfma_f32_16x16x32_bf16(af[i], bfr[j], acc[i][j], 0, 0, 0);
        __syncthreads();
    }

    const int ep = blockIdx.x >> 2;   // 4 m-tiles per episode
#pragma unroll
    for (int i = 0; i < 4; ++i) {
#pragma unroll
        for (int j = 0; j < 4; ++j) {
            const int ccol = nbase + n0 + j * 16 + col;
#pragma unroll
            for (int r = 0; r < 4; ++r) {
                const int crow = mbase + m0 + i * 16 + quad * 4 + r;
                float v = acc[i][j][r];
                if (HAS_B) v += bias[ccol];
                if (HAS_T) v += tvec[ep * DD + ccol];
                if (ACT)   v = gelu_f(v);
                if (OUT_F32) OF[(size_t)crow * DD + ccol] = v;
                else         O[(size_t)crow * DD + ccol] = f2bf(v);
            }
        }
    }
}

// ---------------------------------------------------------------------------
// MFMA attention: per (64 q-rows, h, b). S=Q·K^T (MFMA, K rows are B-layout),
// register softmax (quad-group shfl reduce), P->LDS chunk -> P·V^T MFMA.
// ---------------------------------------------------------------------------
__global__ __launch_bounds__(256) void attn_mfma(
    const u16* __restrict__ Q, const u16* __restrict__ K,
    const u16* __restrict__ V, u16* __restrict__ O)
{
    __shared__ __align__(16) u16 Vt[32][520];       // [dk][key], pad 8
    __shared__ __align__(16) u16 Pc[4][16][136];    // per-wave P chunk [q][key]
    const int tid = threadIdx.x, wave = tid >> 6, lane = tid & 63;
    const int col = lane & 15, quad = lane >> 4;
    const int b = blockIdx.z, h = blockIdx.y;
    const size_t base = ((size_t)b * NN) * DD + h * 32;
    const int q0 = blockIdx.x * 64 + wave * 16;

    // stage V transposed: [key][dk] -> Vt[dk][key]
#pragma unroll
    for (int rr = 0; rr < 2; ++rr) {
        const int key = tid + rr * 256;
        const u16* src = V + base + (size_t)key * DD;
#pragma unroll
        for (int c = 0; c < 4; ++c) {
            short8 v = *(const short8*)(src + c * 8);
#pragma unroll
            for (int j = 0; j < 8; ++j) Vt[c * 8 + j][key] = (u16)v[j];
        }
    }
    __syncthreads();

    // S = Q K^T  (DK=32 = one MFMA K-step per 16-key tile)
    const short8 aq = *(const short8*)(Q + base + (size_t)(q0 + col) * DD + quad * 8);
    f32x4 s[32];
#pragma unroll
    for (int kt = 0; kt < 32; ++kt) {
        short8 bk = *(const short8*)(K + base + (size_t)(kt * 16 + col) * DD + quad * 8);
        f32x4 z = {0.f, 0.f, 0.f, 0.f};
        s[kt] = __builtin_amdgcn_mfma_f32_16x16x32_bf16(aq, bk, z, 0, 0, 0);
    }
    const float scale = 0.17677669529663689f;   // 1/sqrt(32)
    float rmax[4] = {-1e30f, -1e30f, -1e30f, -1e30f};
#pragma unroll
    for (int kt = 0; kt < 32; ++kt)
#pragma unroll
        for (int r = 0; r < 4; ++r) {
            float v = s[kt][r] * scale; s[kt][r] = v; rmax[r] = fmaxf(rmax[r], v);
        }
#pragma unroll
    for (int r = 0; r < 4; ++r) {
        rmax[r] = fmaxf(rmax[r], __shfl_xor(rmax[r], 1, 64));
        rmax[r] = fmaxf(rmax[r], __shfl_xor(rmax[r], 2, 64));
        rmax[r] = fmaxf(rmax[r], __shfl_xor(rmax[r], 4, 64));
        rmax[r] = fmaxf(rmax[r], __shfl_xor(rmax[r], 8, 64));
    }
    float lsum[4] = {0.f, 0.f, 0.f, 0.f};
#pragma unroll
    for (int kt = 0; kt < 32; ++kt)
#pragma unroll
        for (int r = 0; r < 4; ++r) {
            float p = __expf(s[kt][r] - rmax[r]); s[kt][r] = p; lsum[r] += p;
        }
#pragma unroll
    for (int r = 0; r < 4; ++r) {
        lsum[r] += __shfl_xor(lsum[r], 1, 64);
        lsum[r] += __shfl_xor(lsum[r], 2, 64);
        lsum[r] += __shfl_xor(lsum[r], 4, 64);
        lsum[r] += __shfl_xor(lsum[r], 8, 64);
    }

    f32x4 oacc[2];
    oacc[0] = (f32x4){0.f, 0.f, 0.f, 0.f};
    oacc[1] = (f32x4){0.f, 0.f, 0.f, 0.f};
#pragma unroll
    for (int chunk = 0; chunk < 4; ++chunk) {
        // C-layout P -> A-layout via per-wave LDS round trip
#pragma unroll
        for (int kt2 = 0; kt2 < 8; ++kt2) {
            const int kt = chunk * 8 + kt2;
#pragma unroll
            for (int r = 0; r < 4; ++r)
                Pc[wave][quad * 4 + r][kt2 * 16 + col] = f2bf(s[kt][r]);
        }
#pragma unroll
        for (int ks = 0; ks < 4; ++ks) {
            short8 ap = *(const short8*)&Pc[wave][col][ks * 32 + quad * 8];
#pragma unroll
            for (int nt = 0; nt < 2; ++nt) {
                short8 bv = *(const short8*)&Vt[nt * 16 + col][chunk * 128 + ks * 32 + quad * 8];
                oacc[nt] = __builtin_amdgcn_mfma_f32_16x16x32_bf16(ap, bv, oacc[nt], 0, 0, 0);
            }
        }
    }
#pragma unroll
    for (int nt = 0; nt < 2; ++nt)
#pragma unroll
        for (int r = 0; r < 4; ++r) {
            float v = oacc[nt][r] / lsum[r];
            O[base + (size_t)(q0 + quad * 4 + r) * DD + nt * 16 + col] = f2bf(v);
        }
}

// ---------------------------------------------------------------------------
// convert helpers
// ---------------------------------------------------------------------------
__global__ __launch_bounds__(256) void convert_emb(
    const float* __restrict__ e, u16* __restrict__ E, u16* __restrict__ G)
{
    const size_t i = ((size_t)blockIdx.x * 256 + threadIdx.x) * 4;
    const float4 v = *(const float4*)(e + i);
    ushort4 ev, gv;
    ev.x = f2bf(v.x); ev.y = f2bf(v.y); ev.z = f2bf(v.z); ev.w = f2bf(v.w);
    gv.x = f2bf(gelu_f(v.x)); gv.y = f2bf(gelu_f(v.y));
    gv.z = f2bf(gelu_f(v.z)); gv.w = f2bf(gelu_f(v.w));
    *(ushort4*)(E + i) = ev;
    *(ushort4*)(G + i) = gv;
}

__global__ __launch_bounds__(256) void convert_w(
    const float* s0, const float* s1, const float* s2, const float* s3,
    const float* s4, const float* s5, const float* s6, const float* s7,
    const float* s8, const float* s9, u16* __restrict__ Wt)
{
    const int my = blockIdx.y;
    const int kb = blockIdx.x * 16;
    const int n = threadIdx.x;
    const float* S;
    switch (my) {
        case 0: S = s0; break; case 1: S = s1; break; case 2: S = s2; break;
        case 3: S = s3; break; case 4: S = s4; break; case 5: S = s5; break;
        case 6: S = s6; break; case 7: S = s7; break; case 8: S = s8; break;
        default: S = s9; break;
    }
    u16* Dst = Wt + (size_t)my * 65536;
    for (int r = 0; r < 16; ++r) {
        const int k = kb + r;
        Dst[(size_t)n * 256 + k] = f2bf(S[(size_t)k * 256 + n]);  // transpose
    }
}

// ---------------------------------------------------------------------------
// aggr: aggr=gelu(mean X2); a2=gelu(aggr@resW+resb); tvec=a2@ffW1[0:256,:]
// ---------------------------------------------------------------------------
__global__ __launch_bounds__(256) void aggr_kernel(
    const float* __restrict__ X, const float* __restrict__ resW,
    const float* __restrict__ resb, const float* __restrict__ W1,
    float* __restrict__ tvec)
{
    const int b = blockIdx.x, d = threadIdx.x;
    const float* Xb = X + (size_t)b * NN * DD;
    __shared__ float a[256], a2[256];
    float s = 0.f;
    for (int n = 0; n < NN; ++n) s += Xb[(size_t)n * DD + d];
    a[d] = gelu_f(s * (1.0f / NN));
    __syncthreads();
    float t = resb[d];
    for (int k = 0; k < 256; ++k) t += a[k] * resW[(size_t)k * 256 + d];
    a2[d] = gelu_f(t);
    __syncthreads();
    float u = 0.f;
    for (int k = 0; k < 256; ++k) u += a2[k] * W1[(size_t)k * 256 + d];
    tvec[b * 256 + d] = u;
}

// ---------------------------------------------------------------------------
// class sums over 64-d chunks; grid (B, 4); 4 waves split the 512 rows
// ---------------------------------------------------------------------------
__global__ __launch_bounds__(256) void classsum_kernel(
    const float* __restrict__ F, const int* __restrict__ labels,
    float* __restrict__ g, float* __restrict__ counts)
{
    const int b = blockIdx.x, dch = blockIdx.y;
    const int t = threadIdx.x, w = t >> 6, lane = t & 63;
    __shared__ int lab[NN];
    __shared__ float gs[4][CC][64];
    lab[t] = labels[b * NN + t];
    lab[t + 256] = labels[b * NN + t + 256];
#pragma unroll
    for (int c = 0; c < CC; ++c) gs[w][c][lane] = 0.f;
    __syncthreads();
    const float* Fb = F + (size_t)b * NN * DD + dch * 64;
    for (int n = w * 128; n < w * 128 + 128; ++n)
        gs[w][lab[n]][lane] += Fb[(size_t)n * DD + lane];
    __syncthreads();
#pragma unroll
    for (int i = 0; i < 4; ++i) {
        const int c = w * 4 + i;
        const float v = gs[0][c][lane] + gs[1][c][lane] + gs[2][c][lane] + gs[3][c][lane];
        g[((size_t)b * CC + c) * DD + dch * 64 + lane] = v;
    }
    if (dch == 0 && t < CC) {
        int cnt = 0;
        for (int n = 0; n < NN; ++n) cnt += (lab[n] == t);
        counts[b * CC + t] = (float)cnt;
    }
}

// ---------------------------------------------------------------------------
// out[b,n,c] = (f_n·g[c] - [lab==c]*||f_n||^2) / (counts[c]-[lab==c])
// ---------------------------------------------------------------------------
__global__ __launch_bounds__(256) void out_kernel(
    const float* __restrict__ F, const int* __restrict__ labels,
    const float* __restrict__ g, const float* __restrict__ counts,
    float* __restrict__ out)
{
    const int b = blockIdx.y;
    const int wave = threadIdx.x >> 6, lane = threadIdx.x & 63;
    const int n = blockIdx.x * 4 + wave;

    const float* fn = F + ((size_t)b * NN + n) * DD;
    const float* gb = g + (size_t)b * CC * DD;

    float fv[4];
#pragma unroll
    for (int i = 0; i < 4; ++i) fv[i] = fn[lane * 4 + i];
    float selfdot = 0.f;
#pragma unroll
    for (int i = 0; i < 4; ++i) selfdot += fv[i] * fv[i];

    float accs[CC];
#pragma unroll
    for (int c = 0; c < CC; ++c) {
        float sacc = 0.f;
#pragma unroll
        for (int i = 0; i < 4; ++i) sacc += fv[i] * gb[c * DD + lane * 4 + i];
        accs[c] = sacc;
    }
    for (int off = 32; off; off >>= 1) {
        selfdot += __shfl_xor(selfdot, off, 64);
#pragma unroll
        for (int c = 0; c < CC; ++c) accs[c] += __shfl_xor(accs[c], off, 64);
    }
    if (lane < CC) {
        const int c = lane;
        const int same = (labels[b * NN + n] == c) ? 1 : 0;
        const float num = accs[c] - (same ? selfdot : 0.f);
        const float den = counts[b * CC + c] - (float)same;
        out[((size_t)b * NN + n) * CC + c] = num / den;
    }
}

// ---------------------------------------------------------------------------
extern "C" void kernel_launch(void* const* d_in, const int* in_sizes, int n_in,
                              void* d_out, int out_size, void* d_ws, size_t ws_size,
                              hipStream_t stream)
{
    const float* emb    = (const float*)d_in[0];
    const int*   labels = (const int*)  d_in[1];
    const float* Wq0 = (const float*)d_in[2];
    const float* Wk0 = (const float*)d_in[3];
    const float* Wv0 = (const float*)d_in[4];
    const float* Wo0 = (const float*)d_in[5];
    const float* Wq1 = (const float*)d_in[6];
    const float* Wk1 = (const float*)d_in[7];
    const float* Wv1 = (const float*)d_in[8];
    const float* Wo1 = (const float*)d_in[9];
    const float* resW = (const float*)d_in[10];
    const float* resb = (const float*)d_in[11];
    const float* ffW1 = (const float*)d_in[12];
    const float* ffb1 = (const float*)d_in[13];
    const float* ffW2 = (const float*)d_in[14];
    const float* ffb2 = (const float*)d_in[15];
    float* out = (float*)d_out;

    const size_t SBE = (size_t)BB * NN * DD;   // 2,097,152 elems
    u16* BUF0 = (u16*)d_ws;          // E_bf, later X1
    u16* BUF1 = BUF0 + SBE;          // G_bf = gelu(emb)
    u16* BUF2 = BUF1 + SBE;          // Q
    u16* BUF3 = BUF2 + SBE;          // K, later H
    u16* BUF4 = BUF3 + SBE;          // V
    u16* BUF5 = BUF4 + SBE;          // attn out
    u16* Wt   = BUF5 + SBE;          // 10 x [256x256] bf16 transposed
    float* F     = (float*)(Wt + 10 * 65536);   // [8192x256] fp32 (X2, then features)
    float* tvec  = F + SBE;                     // [B,256]
    float* gsum  = tvec + BB * 256;             // [B,C,256]
    float* counts = gsum + (size_t)BB * CC * DD;

    convert_emb<<<2048, 256, 0, stream>>>(emb, BUF0, BUF1);
    convert_w<<<dim3(16, 10), 256, 0, stream>>>(Wq0, Wk0, Wv0, Wo0, Wq1, Wk1, Wv1, Wo1,
                                                ffW1 + 256 * 256, ffW2, Wt);
    // QKV0
    gemm_bf16<0,0,0,0><<<dim3(64, 6), 256, 0, stream>>>(
        BUF0, Wt, Wt + 65536, Wt + 2 * 65536, BUF2, BUF3, BUF4, nullptr, nullptr, nullptr);
    attn_mfma<<<dim3(8, HH, BB), 256, 0, stream>>>(BUF2, BUF3, BUF4, BUF5);
    // X1 = gelu(attn0 @ Wo0)
    gemm_bf16<1,0,0,0><<<dim3(64, 2), 256, 0, stream>>>(
        BUF5, Wt + 3 * 65536, Wt + 3 * 65536, Wt + 3 * 65536, BUF0, BUF0, BUF0, nullptr, nullptr, nullptr);
    // QKV1
    gemm_bf16<0,0,0,0><<<dim3(64, 6), 256, 0, stream>>>(
        BUF0, Wt + 4 * 65536, Wt + 5 * 65536, Wt + 6 * 65536, BUF2, BUF3, BUF4, nullptr, nullptr, nullptr);
    attn_mfma<<<dim3(8, HH, BB), 256, 0, stream>>>(BUF2, BUF3, BUF4, BUF5);
    // X2 = attn1 @ Wo1  (fp32 out -> F; only feeds aggr)
    gemm_bf16<0,0,0,1><<<dim3(64, 2), 256, 0, stream>>>(
        BUF5, Wt + 7 * 65536, Wt + 7 * 65536, Wt + 7 * 65536, BUF2, BUF2, BUF2, F, nullptr, nullptr);
    aggr_kernel<<<BB, 256, 0, stream>>>(F, resW, resb, ffW1, tvec);
    // H = gelu(G @ W1e + tvec + b1)
    gemm_bf16<1,1,1,0><<<dim3(64, 2), 256, 0, stream>>>(
        BUF1, Wt + 8 * 65536, Wt + 8 * 65536, Wt + 8 * 65536, BUF3, BUF3, BUF3, nullptr, ffb1, tvec);
    // F = H @ W2 + b2  (fp32)
    gemm_bf16<0,1,0,1><<<dim3(64, 2), 256, 0, stream>>>(
        BUF3, Wt + 9 * 65536, Wt + 9 * 65536, Wt + 9 * 65536, BUF4, BUF4, BUF4, F, ffb2, nullptr);
    classsum_kernel<<<dim3(BB, 4), 256, 0, stream>>>(F, labels, gsum, counts);
    out_kernel<<<dim3(128, BB), 256, 0, stream>>>(F, labels, gsum, counts, out);
}

// Round 3
// 222.587 us; speedup vs baseline: 3.2116x; 1.5780x over previous
//
#include <hip/hip_runtime.h>

#define BB 16
#define NN 512
#define DD 256
#define HH 8
#define CC 16

typedef unsigned short u16;
using short8 = __attribute__((ext_vector_type(8))) short;
using f32x4  = __attribute__((ext_vector_type(4))) float;

__device__ __forceinline__ float gelu_f(float x) {
    return 0.5f * x * (1.0f + erff(x * 0.70710678118654752f));
}
__device__ __forceinline__ u16 f2bf(float f) {
    unsigned int u = __float_as_uint(f);
    unsigned int r = u + 0x7FFFu + ((u >> 16) & 1u);
    return (u16)(r >> 16);
}
// async global->LDS, 16B/lane; LDS dest = wave-uniform base + lane*16
__device__ __forceinline__ void gld16(const u16* g, const u16* l) {
    __builtin_amdgcn_global_load_lds(
        (const __attribute__((address_space(1))) unsigned int*)g,
        (__attribute__((address_space(3))) unsigned int*)l, 16, 0, 0);
}

// ---------------------------------------------------------------------------
// 64x64-tile bf16 MFMA GEMM (BK=32). A: [8192 x 256] bf16 row-major,
// W: [256 n x 256 k] bf16 (pre-transposed). grid.x = 128 m-tiles.
// QKV=0: grid.y = 4 n-tiles, O = O0 (token-major) or OF fp32.
// QKV=1: grid.y = 12 (sel = y>>2 picks Q/K/V): Q,K head-major [b,h,n,32]
//        (Q scaled 1/sqrt(32)), V transposed [b,h,32,n].
// ---------------------------------------------------------------------------
template<int ACT, int HAS_B, int HAS_T, int OUT_F32, int QKV>
__global__ __launch_bounds__(256) void gemm64(
    const u16* __restrict__ A,
    const u16* __restrict__ W0, const u16* __restrict__ W1, const u16* __restrict__ W2,
    u16* __restrict__ O0, u16* __restrict__ O1, u16* __restrict__ O2,
    float* __restrict__ OF,
    const float* __restrict__ bias, const float* __restrict__ tvec)
{
    __shared__ __align__(16) u16 As[64 * 32];
    __shared__ __align__(16) u16 Bs[64 * 32];
    const int tid = threadIdx.x, wave = tid >> 6, lane = tid & 63;
    const int col = lane & 15, quad = lane >> 4;
    const int mbase = blockIdx.x * 64;
    int sel, nbase;
    if (QKV) { sel = blockIdx.y >> 2; nbase = (blockIdx.y & 3) * 64; }
    else     { sel = 0;               nbase = blockIdx.y * 64; }
    const u16* W = (sel == 0) ? W0 : ((sel == 1) ? W1 : W2);
    u16* O = (sel == 0) ? O0 : ((sel == 1) ? O1 : O2);
    const int srow = lane >> 2, skk = (lane & 3) * 8;
    const int mh = (wave & 1) * 32, nh = (wave >> 1) * 32;

    f32x4 acc[2][2];
#pragma unroll
    for (int i = 0; i < 2; ++i)
#pragma unroll
        for (int j = 0; j < 2; ++j) acc[i][j] = (f32x4){0.f, 0.f, 0.f, 0.f};

    for (int k0 = 0; k0 < DD; k0 += 32) {
        gld16(A + (size_t)(mbase + wave * 16 + srow) * DD + k0 + skk, &As[wave * 512]);
        gld16(W + (size_t)(nbase + wave * 16 + srow) * DD + k0 + skk, &Bs[wave * 512]);
        __syncthreads();
        short8 af[2], bfr[2];
#pragma unroll
        for (int i = 0; i < 2; ++i) af[i]  = *(const short8*)&As[(mh + i * 16 + col) * 32 + quad * 8];
#pragma unroll
        for (int j = 0; j < 2; ++j) bfr[j] = *(const short8*)&Bs[(nh + j * 16 + col) * 32 + quad * 8];
#pragma unroll
        for (int i = 0; i < 2; ++i)
#pragma unroll
            for (int j = 0; j < 2; ++j)
                acc[i][j] = __builtin_amdgcn_mfma_f32_16x16x32_bf16(af[i], bfr[j], acc[i][j], 0, 0, 0);
        __syncthreads();
    }

    const int b = mbase >> 9;   // episode
#pragma unroll
    for (int i = 0; i < 2; ++i) {
#pragma unroll
        for (int j = 0; j < 2; ++j) {
            const int ccol = nbase + nh + j * 16 + col;
            const int tok0 = (mbase & 511) + mh + i * 16 + quad * 4;
            if (QKV) {
                const int head = ccol >> 5, dk = ccol & 31;
                if (sel == 2) {
                    ushort4 pk;
                    pk.x = f2bf(acc[i][j][0]); pk.y = f2bf(acc[i][j][1]);
                    pk.z = f2bf(acc[i][j][2]); pk.w = f2bf(acc[i][j][3]);
                    *(ushort4*)&O[(((size_t)b * HH + head) * 32 + dk) * NN + tok0] = pk;
                } else {
#pragma unroll
                    for (int r = 0; r < 4; ++r) {
                        float v = acc[i][j][r];
                        if (sel == 0) v *= 0.17677669529663689f;
                        O[(((size_t)b * HH + head) * NN + tok0 + r) * 32 + dk] = f2bf(v);
                    }
                }
            } else {
#pragma unroll
                for (int r = 0; r < 4; ++r) {
                    const int crow = mbase + mh + i * 16 + quad * 4 + r;
                    float v = acc[i][j][r];
                    if (HAS_B) v += bias[ccol];
                    if (HAS_T) v += tvec[b * DD + ccol];
                    if (ACT)   v = gelu_f(v);
                    if (OUT_F32) OF[(size_t)crow * DD + ccol] = v;
                    else         O[(size_t)crow * DD + ccol] = f2bf(v);
                }
            }
        }
    }
}

// ---------------------------------------------------------------------------
// Flash MFMA attention. Qh,Kh: [b,h,n,32] (Q pre-scaled), VT: [b,h,32,n].
// 1-D grid 1024: gid = qb*128 + (b*8+h)  -> all q-blocks of a (b,h) share XCD.
// Block 256 thr / 4 waves; wave = 16 q rows; flash over 4 chunks of 128 keys.
// ---------------------------------------------------------------------------
__global__ __launch_bounds__(256) void attn_mfma(
    const u16* __restrict__ Qh, const u16* __restrict__ Kh,
    const u16* __restrict__ VT, u16* __restrict__ O)
{
    __shared__ __align__(16) u16 Vt[32 * 520];      // [dk][key], pad 8
    __shared__ __align__(16) u16 Pc[4][16 * 32];    // per-wave P sub-chunk
    const int tid = threadIdx.x, wave = tid >> 6, lane = tid & 63;
    const int col = lane & 15, quad = lane >> 4;
    const int gid = blockIdx.x;
    const int qb = gid >> 7, bh = gid & 127;
    const int b = bh >> 3, h = bh & 7;
    const int q0 = qb * 64 + wave * 16;

    // stage V^T head (32 rows x 512 keys) via async 1KB-per-row loads
    const u16* vsrc = VT + (size_t)bh * 32 * NN;
#pragma unroll
    for (int i = 0; i < 8; ++i) {
        const int row = wave + i * 4;
        gld16(vsrc + (size_t)row * NN + lane * 8, &Vt[row * 520]);
    }
    const short8 aq = *(const short8*)(Qh + ((size_t)bh * NN + q0 + col) * 32 + quad * 8);
    __syncthreads();

    const u16* ksrc = Kh + (size_t)bh * NN * 32;
    float m[4] = {-1e30f, -1e30f, -1e30f, -1e30f};
    float l[4] = {0.f, 0.f, 0.f, 0.f};
    f32x4 oacc[2];
    oacc[0] = (f32x4){0.f, 0.f, 0.f, 0.f};
    oacc[1] = (f32x4){0.f, 0.f, 0.f, 0.f};

    for (int c = 0; c < 4; ++c) {
        f32x4 s[8];
#pragma unroll
        for (int kt = 0; kt < 8; ++kt) {
            const short8 bk = *(const short8*)(ksrc + (size_t)(c * 128 + kt * 16 + col) * 32 + quad * 8);
            f32x4 z = {0.f, 0.f, 0.f, 0.f};
            s[kt] = __builtin_amdgcn_mfma_f32_16x16x32_bf16(aq, bk, z, 0, 0, 0);
        }
        float cm[4], al[4];
#pragma unroll
        for (int r = 0; r < 4; ++r) {
            float v = fmaxf(fmaxf(fmaxf(s[0][r], s[1][r]), fmaxf(s[2][r], s[3][r])),
                            fmaxf(fmaxf(s[4][r], s[5][r]), fmaxf(s[6][r], s[7][r])));
            v = fmaxf(v, __shfl_xor(v, 1, 64));
            v = fmaxf(v, __shfl_xor(v, 2, 64));
            v = fmaxf(v, __shfl_xor(v, 4, 64));
            v = fmaxf(v, __shfl_xor(v, 8, 64));
            cm[r] = v;
        }
#pragma unroll
        for (int r = 0; r < 4; ++r) {
            const float mn = fmaxf(m[r], cm[r]);
            al[r] = __expf(m[r] - mn);
            m[r] = mn;
            l[r] *= al[r];
        }
#pragma unroll
        for (int nt = 0; nt < 2; ++nt)
#pragma unroll
            for (int r = 0; r < 4; ++r) oacc[nt][r] *= al[r];
        // PV in 32-key sub-chunks through per-wave LDS
#pragma unroll
        for (int s2 = 0; s2 < 4; ++s2) {
#pragma unroll
            for (int k2 = 0; k2 < 2; ++k2) {
                const int kt = s2 * 2 + k2;
#pragma unroll
                for (int r = 0; r < 4; ++r) {
                    const float p = __expf(s[kt][r] - m[r]);
                    l[r] += p;
                    Pc[wave][(quad * 4 + r) * 32 + k2 * 16 + col] = f2bf(p);
                }
            }
            const short8 ap = *(const short8*)&Pc[wave][col * 32 + quad * 8];
#pragma unroll
            for (int nt = 0; nt < 2; ++nt) {
                const short8 bv = *(const short8*)&Vt[(nt * 16 + col) * 520 + c * 128 + s2 * 32 + quad * 8];
                oacc[nt] = __builtin_amdgcn_mfma_f32_16x16x32_bf16(ap, bv, oacc[nt], 0, 0, 0);
            }
        }
    }
#pragma unroll
    for (int r = 0; r < 4; ++r) {
        l[r] += __shfl_xor(l[r], 1, 64);
        l[r] += __shfl_xor(l[r], 2, 64);
        l[r] += __shfl_xor(l[r], 4, 64);
        l[r] += __shfl_xor(l[r], 8, 64);
    }
    u16* obase = O + ((size_t)b * NN) * DD + h * 32;
#pragma unroll
    for (int nt = 0; nt < 2; ++nt)
#pragma unroll
        for (int r = 0; r < 4; ++r)
            obase[(size_t)(q0 + quad * 4 + r) * DD + nt * 16 + col] = f2bf(oacc[nt][r] / l[r]);
}

// ---------------------------------------------------------------------------
__global__ __launch_bounds__(256) void convert_emb(
    const float* __restrict__ e, u16* __restrict__ E, u16* __restrict__ G)
{
    const size_t i = ((size_t)blockIdx.x * 256 + threadIdx.x) * 4;
    const float4 v = *(const float4*)(e + i);
    ushort4 ev, gv;
    ev.x = f2bf(v.x); ev.y = f2bf(v.y); ev.z = f2bf(v.z); ev.w = f2bf(v.w);
    gv.x = f2bf(gelu_f(v.x)); gv.y = f2bf(gelu_f(v.y));
    gv.z = f2bf(gelu_f(v.z)); gv.w = f2bf(gelu_f(v.w));
    *(ushort4*)(E + i) = ev;
    *(ushort4*)(G + i) = gv;
}

__global__ __launch_bounds__(256) void convert_w(
    const float* s0, const float* s1, const float* s2, const float* s3,
    const float* s4, const float* s5, const float* s6, const float* s7,
    const float* s8, const float* s9, u16* __restrict__ Wt)
{
    const int my = blockIdx.y;
    const int kb = blockIdx.x * 16;
    const int n = threadIdx.x;
    const float* S;
    switch (my) {
        case 0: S = s0; break; case 1: S = s1; break; case 2: S = s2; break;
        case 3: S = s3; break; case 4: S = s4; break; case 5: S = s5; break;
        case 6: S = s6; break; case 7: S = s7; break; case 8: S = s8; break;
        default: S = s9; break;
    }
    u16* Dst = Wt + (size_t)my * 65536;
    for (int r = 0; r < 16; ++r) {
        const int k = kb + r;
        Dst[(size_t)n * 256 + k] = f2bf(S[(size_t)k * 256 + n]);  // transpose
    }
}

// ---------------------------------------------------------------------------
// aggr stage 1: partial[b][ch][d] = sum of 64 rows
// ---------------------------------------------------------------------------
__global__ __launch_bounds__(256) void aggr1(
    const float* __restrict__ X, float* __restrict__ partial)
{
    const int b = blockIdx.x, ch = blockIdx.y, d = threadIdx.x;
    const float* Xb = X + ((size_t)b * NN + ch * 64) * DD;
    float s = 0.f;
#pragma unroll 8
    for (int n = 0; n < 64; ++n) s += Xb[(size_t)n * DD + d];
    partial[((size_t)b * 8 + ch) * DD + d] = s;
}

// aggr stage 2: aggr=gelu(mean); a2=gelu(aggr@resW+resb); tvec=a2@ffW1[0:256]
__global__ __launch_bounds__(256) void aggr2(
    const float* __restrict__ partial, const float* __restrict__ resW,
    const float* __restrict__ resb, const float* __restrict__ W1,
    float* __restrict__ tvec)
{
    const int b = blockIdx.x, d = threadIdx.x;
    __shared__ float a[256], a2[256];
    float s = 0.f;
#pragma unroll
    for (int ch = 0; ch < 8; ++ch) s += partial[((size_t)b * 8 + ch) * DD + d];
    a[d] = gelu_f(s * (1.0f / NN));
    __syncthreads();
    float t = resb[d];
    for (int k = 0; k < 256; ++k) t += a[k] * resW[(size_t)k * 256 + d];
    a2[d] = gelu_f(t);
    __syncthreads();
    float u = 0.f;
    for (int k = 0; k < 256; ++k) u += a2[k] * W1[(size_t)k * 256 + d];
    tvec[b * 256 + d] = u;
}

// ---------------------------------------------------------------------------
__global__ __launch_bounds__(256) void classsum_kernel(
    const float* __restrict__ F, const int* __restrict__ labels,
    float* __restrict__ g, float* __restrict__ counts)
{
    const int b = blockIdx.x, dch = blockIdx.y;
    const int t = threadIdx.x, w = t >> 6, lane = t & 63;
    __shared__ int lab[NN];
    __shared__ float gs[4][CC][64];
    lab[t] = labels[b * NN + t];
    lab[t + 256] = labels[b * NN + t + 256];
#pragma unroll
    for (int c = 0; c < CC; ++c) gs[w][c][lane] = 0.f;
    __syncthreads();
    const float* Fb = F + (size_t)b * NN * DD + dch * 64;
    for (int n = w * 128; n < w * 128 + 128; ++n)
        gs[w][lab[n]][lane] += Fb[(size_t)n * DD + lane];
    __syncthreads();
#pragma unroll
    for (int i = 0; i < 4; ++i) {
        const int c = w * 4 + i;
        const float v = gs[0][c][lane] + gs[1][c][lane] + gs[2][c][lane] + gs[3][c][lane];
        g[((size_t)b * CC + c) * DD + dch * 64 + lane] = v;
    }
    if (dch == 0 && t < CC) {
        int cnt = 0;
        for (int n = 0; n < NN; ++n) cnt += (lab[n] == t);
        counts[b * CC + t] = (float)cnt;
    }
}

__global__ __launch_bounds__(256) void out_kernel(
    const float* __restrict__ F, const int* __restrict__ labels,
    const float* __restrict__ g, const float* __restrict__ counts,
    float* __restrict__ out)
{
    const int b = blockIdx.y;
    const int wave = threadIdx.x >> 6, lane = threadIdx.x & 63;
    const int n = blockIdx.x * 4 + wave;
    const float* fn = F + ((size_t)b * NN + n) * DD;
    const float* gb = g + (size_t)b * CC * DD;
    float fv[4];
#pragma unroll
    for (int i = 0; i < 4; ++i) fv[i] = fn[lane * 4 + i];
    float selfdot = 0.f;
#pragma unroll
    for (int i = 0; i < 4; ++i) selfdot += fv[i] * fv[i];
    float accs[CC];
#pragma unroll
    for (int c = 0; c < CC; ++c) {
        float sacc = 0.f;
#pragma unroll
        for (int i = 0; i < 4; ++i) sacc += fv[i] * gb[c * DD + lane * 4 + i];
        accs[c] = sacc;
    }
    for (int off = 32; off; off >>= 1) {
        selfdot += __shfl_xor(selfdot, off, 64);
#pragma unroll
        for (int c = 0; c < CC; ++c) accs[c] += __shfl_xor(accs[c], off, 64);
    }
    if (lane < CC) {
        const int c = lane;
        const int same = (labels[b * NN + n] == c) ? 1 : 0;
        const float num = accs[c] - (same ? selfdot : 0.f);
        const float den = counts[b * CC + c] - (float)same;
        out[((size_t)b * NN + n) * CC + c] = num / den;
    }
}

// ---------------------------------------------------------------------------
extern "C" void kernel_launch(void* const* d_in, const int* in_sizes, int n_in,
                              void* d_out, int out_size, void* d_ws, size_t ws_size,
                              hipStream_t stream)
{
    const float* emb    = (const float*)d_in[0];
    const int*   labels = (const int*)  d_in[1];
    const float* resW = (const float*)d_in[10];
    const float* resb = (const float*)d_in[11];
    const float* ffW1 = (const float*)d_in[12];
    const float* ffb1 = (const float*)d_in[13];
    const float* ffb2 = (const float*)d_in[15];
    float* out = (float*)d_out;

    const size_t SBE = (size_t)BB * NN * DD;   // 2,097,152 elems
    u16* BUF0 = (u16*)d_ws;          // E_bf (token-major), later X1
    u16* BUF1 = BUF0 + SBE;          // G_bf = gelu(emb)
    u16* BUF2 = BUF1 + SBE;          // Qh [b,h,n,32]
    u16* BUF3 = BUF2 + SBE;          // Kh, later H
    u16* BUF4 = BUF3 + SBE;          // VT [b,h,32,n]
    u16* BUF5 = BUF4 + SBE;          // attn out (token-major)
    u16* Wt   = BUF5 + SBE;          // 10 x [256n x 256k] bf16 transposed
    float* F      = (float*)(Wt + 10 * 65536);  // [8192x256] fp32
    float* tvec   = F + SBE;                    // [B,256]
    float* partial= tvec + BB * 256;            // [B,8,256]
    float* gsum   = partial + BB * 8 * 256;     // [B,C,256]
    float* counts = gsum + (size_t)BB * CC * DD;

    convert_emb<<<2048, 256, 0, stream>>>(emb, BUF0, BUF1);
    convert_w<<<dim3(16, 10), 256, 0, stream>>>(
        (const float*)d_in[2], (const float*)d_in[3], (const float*)d_in[4],
        (const float*)d_in[5], (const float*)d_in[6], (const float*)d_in[7],
        (const float*)d_in[8], (const float*)d_in[9],
        ffW1 + 256 * 256, (const float*)d_in[14], Wt);
    // QKV0 (head-major outputs, Q scaled, V transposed)
    gemm64<0,0,0,0,1><<<dim3(128, 12), 256, 0, stream>>>(
        BUF0, Wt, Wt + 65536, Wt + 2 * 65536, BUF2, BUF3, BUF4, nullptr, nullptr, nullptr);
    attn_mfma<<<1024, 256, 0, stream>>>(BUF2, BUF3, BUF4, BUF5);
    // X1 = gelu(attn0 @ Wo0)
    gemm64<1,0,0,0,0><<<dim3(128, 4), 256, 0, stream>>>(
        BUF5, Wt + 3 * 65536, nullptr, nullptr, BUF0, nullptr, nullptr, nullptr, nullptr, nullptr);
    // QKV1
    gemm64<0,0,0,0,1><<<dim3(128, 12), 256, 0, stream>>>(
        BUF0, Wt + 4 * 65536, Wt + 5 * 65536, Wt + 6 * 65536, BUF2, BUF3, BUF4, nullptr, nullptr, nullptr);
    attn_mfma<<<1024, 256, 0, stream>>>(BUF2, BUF3, BUF4, BUF5);
    // X2 = attn1 @ Wo1 (fp32 -> F, feeds aggr)
    gemm64<0,0,0,1,0><<<dim3(128, 4), 256, 0, stream>>>(
        BUF5, Wt + 7 * 65536, nullptr, nullptr, nullptr, nullptr, nullptr, F, nullptr, nullptr);
    aggr1<<<dim3(BB, 8), 256, 0, stream>>>(F, partial);
    aggr2<<<BB, 256, 0, stream>>>(partial, resW, resb, ffW1, tvec);
    // H = gelu(gelu(e) @ W1e + tvec + b1)
    gemm64<1,1,1,0,0><<<dim3(128, 4), 256, 0, stream>>>(
        BUF1, Wt + 8 * 65536, nullptr, nullptr, BUF3, nullptr, nullptr, nullptr, ffb1, tvec);
    // F = H @ W2 + b2 (fp32)
    gemm64<0,1,0,1,0><<<dim3(128, 4), 256, 0, stream>>>(
        BUF3, Wt + 9 * 65536, nullptr, nullptr, nullptr, nullptr, nullptr, F, ffb2, nullptr);
    classsum_kernel<<<dim3(BB, 4), 256, 0, stream>>>(F, labels, gsum, counts);
    out_kernel<<<dim3(128, BB), 256, 0, stream>>>(F, labels, gsum, counts, out);
}

// Round 4
// 211.686 us; speedup vs baseline: 3.3770x; 1.0515x over previous
//
#include <hip/hip_runtime.h>

#define BB 16
#define NN 512
#define DD 256
#define HH 8
#define CC 16

typedef unsigned short u16;
using short8 = __attribute__((ext_vector_type(8))) short;
using f32x4  = __attribute__((ext_vector_type(4))) float;

__device__ __forceinline__ float gelu_f(float x) {
    return 0.5f * x * (1.0f + erff(x * 0.70710678118654752f));
}
__device__ __forceinline__ u16 f2bf(float f) {
    unsigned int u = __float_as_uint(f);
    unsigned int r = u + 0x7FFFu + ((u >> 16) & 1u);
    return (u16)(r >> 16);
}
// async global->LDS, 16B/lane; LDS dest = wave-uniform base + lane*16
__device__ __forceinline__ void gld16(const u16* g, const u16* l) {
    __builtin_amdgcn_global_load_lds(
        (const __attribute__((address_space(1))) unsigned int*)g,
        (__attribute__((address_space(3))) unsigned int*)l, 16, 0, 0);
}

// Q pre-scale: (1/sqrt(32)) * log2(e)  -> attention uses exp2
#define QSCALE 0.25505412f

// ---------------------------------------------------------------------------
// 64x64-tile bf16 MFMA GEMM (BK=32). A: [8192 x 256] bf16 row-major,
// W: [256 n x 256 k] bf16 (pre-transposed). grid.x = 128 m-tiles.
// QKV=0: grid.y = 4 n-tiles; out token-major bf16 (or fp32 OF).
// QKV=1: grid.y = 12 (sel=y>>2 picks Q/K/V): Q,K head-major [b,h,n,32]
//        (Q scaled QSCALE), V transposed [b,h,32,n].
// ---------------------------------------------------------------------------
template<int ACT, int HAS_B, int HAS_T, int OUT_F32, int QKV>
__global__ __launch_bounds__(256) void gemm64(
    const u16* __restrict__ A,
    const u16* __restrict__ W0, const u16* __restrict__ W1, const u16* __restrict__ W2,
    u16* __restrict__ O0, u16* __restrict__ O1, u16* __restrict__ O2,
    float* __restrict__ OF,
    const float* __restrict__ bias, const float* __restrict__ tvec)
{
    __shared__ __align__(16) u16 As[64 * 32];
    __shared__ __align__(16) u16 Bs[64 * 32];
    const int tid = threadIdx.x, wave = tid >> 6, lane = tid & 63;
    const int col = lane & 15, quad = lane >> 4;
    const int mbase = blockIdx.x * 64;
    int sel, nbase;
    if (QKV) { sel = blockIdx.y >> 2; nbase = (blockIdx.y & 3) * 64; }
    else     { sel = 0;               nbase = blockIdx.y * 64; }
    const u16* W = (sel == 0) ? W0 : ((sel == 1) ? W1 : W2);
    u16* O = (sel == 0) ? O0 : ((sel == 1) ? O1 : O2);
    const int srow = lane >> 2, skk = (lane & 3) * 8;
    const int mh = (wave & 1) * 32, nh = (wave >> 1) * 32;

    f32x4 acc[2][2];
#pragma unroll
    for (int i = 0; i < 2; ++i)
#pragma unroll
        for (int j = 0; j < 2; ++j) acc[i][j] = (f32x4){0.f, 0.f, 0.f, 0.f};

    for (int k0 = 0; k0 < DD; k0 += 32) {
        gld16(A + (size_t)(mbase + wave * 16 + srow) * DD + k0 + skk, &As[wave * 512]);
        gld16(W + (size_t)(nbase + wave * 16 + srow) * DD + k0 + skk, &Bs[wave * 512]);
        __syncthreads();
        short8 af[2], bfr[2];
#pragma unroll
        for (int i = 0; i < 2; ++i) af[i]  = *(const short8*)&As[(mh + i * 16 + col) * 32 + quad * 8];
#pragma unroll
        for (int j = 0; j < 2; ++j) bfr[j] = *(const short8*)&Bs[(nh + j * 16 + col) * 32 + quad * 8];
#pragma unroll
        for (int i = 0; i < 2; ++i)
#pragma unroll
            for (int j = 0; j < 2; ++j)
                acc[i][j] = __builtin_amdgcn_mfma_f32_16x16x32_bf16(af[i], bfr[j], acc[i][j], 0, 0, 0);
        __syncthreads();
    }

    const int b = mbase >> 9;   // episode
#pragma unroll
    for (int i = 0; i < 2; ++i) {
#pragma unroll
        for (int j = 0; j < 2; ++j) {
            const int ccol = nbase + nh + j * 16 + col;
            const int tok0 = (mbase & 511) + mh + i * 16 + quad * 4;
            if (QKV) {
                const int head = ccol >> 5, dk = ccol & 31;
                if (sel == 2) {
                    ushort4 pk;
                    pk.x = f2bf(acc[i][j][0]); pk.y = f2bf(acc[i][j][1]);
                    pk.z = f2bf(acc[i][j][2]); pk.w = f2bf(acc[i][j][3]);
                    *(ushort4*)&O[(((size_t)b * HH + head) * 32 + dk) * NN + tok0] = pk;
                } else {
#pragma unroll
                    for (int r = 0; r < 4; ++r) {
                        float v = acc[i][j][r];
                        if (sel == 0) v *= QSCALE;
                        O[(((size_t)b * HH + head) * NN + tok0 + r) * 32 + dk] = f2bf(v);
                    }
                }
            } else {
#pragma unroll
                for (int r = 0; r < 4; ++r) {
                    const int crow = mbase + mh + i * 16 + quad * 4 + r;
                    float v = acc[i][j][r];
                    if (HAS_B) v += bias[ccol];
                    if (HAS_T) v += tvec[b * DD + ccol];
                    if (ACT)   v = gelu_f(v);
                    if (OUT_F32) OF[(size_t)crow * DD + ccol] = v;
                    else         O[(size_t)crow * DD + ccol] = f2bf(v);
                }
            }
        }
    }
}

// ---------------------------------------------------------------------------
// Flash MFMA attention, no-max softmax (scores pre-scaled by log2e/sqrt(dk),
// exp2; |s|<<128 so no overflow). Qh,Kh: [b,h,n,32], VT: [b,h,32,n].
// grid 1024: gid = qb*128 + (b*8+h) -> q-blocks of a (b,h) share an XCD.
// COLSUM=1: layer-2 variant — only writes per-block column sums of O
// (feeds mean(x2) @ Wo1 in aggr2); no O write.
// ---------------------------------------------------------------------------
template<int COLSUM>
__global__ __launch_bounds__(256) void attn_mfma(
    const u16* __restrict__ Qh, const u16* __restrict__ Kh,
    const u16* __restrict__ VT, u16* __restrict__ O,
    float* __restrict__ partial)
{
    __shared__ __align__(16) u16 Vt[32 * 520];      // [dk][key], pad 8
    __shared__ __align__(16) u16 Pc[4][16 * 32];    // per-wave P chunk [q][32key]
    __shared__ float cs[4][32];
    const int tid = threadIdx.x, wave = tid >> 6, lane = tid & 63;
    const int col = lane & 15, quad = lane >> 4;
    const int gid = blockIdx.x;
    const int qb = gid >> 7, bh = gid & 127;
    const int q0 = qb * 64 + wave * 16;

    const u16* vsrc = VT + (size_t)bh * 32 * NN;
#pragma unroll
    for (int i = 0; i < 8; ++i) {
        const int row = wave + i * 4;
        gld16(vsrc + (size_t)row * NN + lane * 8, &Vt[row * 520]);
    }
    const short8 aq = *(const short8*)(Qh + ((size_t)bh * NN + q0 + col) * 32 + quad * 8);
    __syncthreads();

    const u16* ksrc = Kh + (size_t)bh * NN * 32;
    float l[4] = {0.f, 0.f, 0.f, 0.f};
    f32x4 oacc[2];
    oacc[0] = (f32x4){0.f, 0.f, 0.f, 0.f};
    oacc[1] = (f32x4){0.f, 0.f, 0.f, 0.f};

    for (int g = 0; g < 16; ++g) {          // 32-key groups
#pragma unroll
        for (int k2 = 0; k2 < 2; ++k2) {
            const int kt = g * 2 + k2;
            const short8 bk = *(const short8*)(ksrc + (size_t)(kt * 16 + col) * 32 + quad * 8);
            f32x4 z = {0.f, 0.f, 0.f, 0.f};
            const f32x4 s = __builtin_amdgcn_mfma_f32_16x16x32_bf16(aq, bk, z, 0, 0, 0);
#pragma unroll
            for (int r = 0; r < 4; ++r) {
                const float p = exp2f(s[r]);
                l[r] += p;
                Pc[wave][(quad * 4 + r) * 32 + k2 * 16 + col] = f2bf(p);
            }
        }
        const short8 ap = *(const short8*)&Pc[wave][col * 32 + quad * 8];
#pragma unroll
        for (int nt = 0; nt < 2; ++nt) {
            const short8 bv = *(const short8*)&Vt[(nt * 16 + col) * 520 + g * 32 + quad * 8];
            oacc[nt] = __builtin_amdgcn_mfma_f32_16x16x32_bf16(ap, bv, oacc[nt], 0, 0, 0);
        }
    }
#pragma unroll
    for (int r = 0; r < 4; ++r) {
        l[r] += __shfl_xor(l[r], 1, 64);
        l[r] += __shfl_xor(l[r], 2, 64);
        l[r] += __shfl_xor(l[r], 4, 64);
        l[r] += __shfl_xor(l[r], 8, 64);
    }
    if (COLSUM) {
        // column sums of O over this block's 64 q rows -> partial[bh*8+qb][32]
        float sv[2] = {0.f, 0.f};
#pragma unroll
        for (int nt = 0; nt < 2; ++nt) {
#pragma unroll
            for (int r = 0; r < 4; ++r) sv[nt] += oacc[nt][r] / l[r];
            sv[nt] += __shfl_xor(sv[nt], 16, 64);
            sv[nt] += __shfl_xor(sv[nt], 32, 64);
        }
        if (lane < 16) { cs[wave][col] = sv[0]; cs[wave][16 + col] = sv[1]; }
        __syncthreads();
        if (tid < 32)
            partial[(size_t)(bh * 8 + qb) * 32 + tid] =
                cs[0][tid] + cs[1][tid] + cs[2][tid] + cs[3][tid];
    } else {
        const int b = bh >> 3, h = bh & 7;
        u16* obase = O + ((size_t)b * NN) * DD + h * 32;
#pragma unroll
        for (int nt = 0; nt < 2; ++nt)
#pragma unroll
            for (int r = 0; r < 4; ++r)
                obase[(size_t)(q0 + quad * 4 + r) * DD + nt * 16 + col] = f2bf(oacc[nt][r] / l[r]);
    }
}

// ---------------------------------------------------------------------------
// merged conversion: blocks [0,2048) emb -> E_bf + gelu(E)_bf;
// blocks [2048, 2048+144): 9 weights transposed to bf16 [n][k]
// ---------------------------------------------------------------------------
__global__ __launch_bounds__(256) void convert_all(
    const float* __restrict__ e, u16* __restrict__ E, u16* __restrict__ G,
    const float* s0, const float* s1, const float* s2, const float* s3,
    const float* s4, const float* s5, const float* s6, const float* s7,
    const float* s8, u16* __restrict__ Wt)
{
    const int bx = blockIdx.x;
    if (bx < 2048) {
        const size_t i = ((size_t)bx * 256 + threadIdx.x) * 4;
        const float4 v = *(const float4*)(e + i);
        ushort4 ev, gv;
        ev.x = f2bf(v.x); ev.y = f2bf(v.y); ev.z = f2bf(v.z); ev.w = f2bf(v.w);
        gv.x = f2bf(gelu_f(v.x)); gv.y = f2bf(gelu_f(v.y));
        gv.z = f2bf(gelu_f(v.z)); gv.w = f2bf(gelu_f(v.w));
        *(ushort4*)(E + i) = ev;
        *(ushort4*)(G + i) = gv;
    } else {
        const int w = bx - 2048;
        const int my = w >> 4, kb = (w & 15) * 16;
        const int n = threadIdx.x;
        const float* S;
        switch (my) {
            case 0: S = s0; break; case 1: S = s1; break; case 2: S = s2; break;
            case 3: S = s3; break; case 4: S = s4; break; case 5: S = s5; break;
            case 6: S = s6; break; case 7: S = s7; break; default: S = s8; break;
        }
        u16* Dst = Wt + (size_t)my * 65536;
        for (int r = 0; r < 16; ++r) {
            const int k = kb + r;
            Dst[(size_t)n * 256 + k] = f2bf(S[(size_t)k * 256 + n]);  // transpose
        }
    }
}

// ---------------------------------------------------------------------------
// aggr: m1 = mean(attn1 colsums); y=m1@Wo1; a1=gelu(y); a2=gelu(a1@resW+resb);
// tvec = a2 @ ffW1[0:256,:]   (all fp32 weights, coalesced column reads)
// ---------------------------------------------------------------------------
__global__ __launch_bounds__(256) void aggr_kernel(
    const float* __restrict__ partial, const float* __restrict__ Wo1f,
    const float* __restrict__ resW, const float* __restrict__ resb,
    const float* __restrict__ W1, float* __restrict__ tvec)
{
    const int b = blockIdx.x, d = threadIdx.x;
    __shared__ float a0[256], a1[256], a2[256];
    const int h = d >> 5, d32 = d & 31;
    float s = 0.f;
#pragma unroll
    for (int qb = 0; qb < 8; ++qb)
        s += partial[(size_t)(((b * 8 + h) * 8) + qb) * 32 + d32];
    a0[d] = s * (1.0f / NN);
    __syncthreads();
    float y = 0.f;
    for (int k = 0; k < 256; ++k) y += a0[k] * Wo1f[(size_t)k * 256 + d];
    a1[d] = gelu_f(y);
    __syncthreads();
    float t = resb[d];
    for (int k = 0; k < 256; ++k) t += a1[k] * resW[(size_t)k * 256 + d];
    a2[d] = gelu_f(t);
    __syncthreads();
    float u = 0.f;
    for (int k = 0; k < 256; ++k) u += a2[k] * W1[(size_t)k * 256 + d];
    tvec[b * 256 + d] = u;
}

// ---------------------------------------------------------------------------
__global__ __launch_bounds__(256) void classsum_kernel(
    const float* __restrict__ F, const int* __restrict__ labels,
    float* __restrict__ g, float* __restrict__ counts)
{
    const int b = blockIdx.x, dch = blockIdx.y;
    const int t = threadIdx.x, w = t >> 6, lane = t & 63;
    __shared__ int lab[NN];
    __shared__ float gs[4][CC][64];
    lab[t] = labels[b * NN + t];
    lab[t + 256] = labels[b * NN + t + 256];
#pragma unroll
    for (int c = 0; c < CC; ++c) gs[w][c][lane] = 0.f;
    __syncthreads();
    const float* Fb = F + (size_t)b * NN * DD + dch * 64;
    for (int n = w * 128; n < w * 128 + 128; ++n)
        gs[w][lab[n]][lane] += Fb[(size_t)n * DD + lane];
    __syncthreads();
#pragma unroll
    for (int i = 0; i < 4; ++i) {
        const int c = w * 4 + i;
        const float v = gs[0][c][lane] + gs[1][c][lane] + gs[2][c][lane] + gs[3][c][lane];
        g[((size_t)b * CC + c) * DD + dch * 64 + lane] = v;
    }
    if (dch == 0 && t < CC) {
        int cnt = 0;
        for (int n = 0; n < NN; ++n) cnt += (lab[n] == t);
        counts[b * CC + t] = (float)cnt;
    }
}

__global__ __launch_bounds__(256) void out_kernel(
    const float* __restrict__ F, const int* __restrict__ labels,
    const float* __restrict__ g, const float* __restrict__ counts,
    float* __restrict__ out)
{
    const int b = blockIdx.y;
    const int wave = threadIdx.x >> 6, lane = threadIdx.x & 63;
    const int n = blockIdx.x * 4 + wave;
    const float* fn = F + ((size_t)b * NN + n) * DD;
    const float* gb = g + (size_t)b * CC * DD;
    float fv[4];
#pragma unroll
    for (int i = 0; i < 4; ++i) fv[i] = fn[lane * 4 + i];
    float selfdot = 0.f;
#pragma unroll
    for (int i = 0; i < 4; ++i) selfdot += fv[i] * fv[i];
    float accs[CC];
#pragma unroll
    for (int c = 0; c < CC; ++c) {
        float sacc = 0.f;
#pragma unroll
        for (int i = 0; i < 4; ++i) sacc += fv[i] * gb[c * DD + lane * 4 + i];
        accs[c] = sacc;
    }
    for (int off = 32; off; off >>= 1) {
        selfdot += __shfl_xor(selfdot, off, 64);
#pragma unroll
        for (int c = 0; c < CC; ++c) accs[c] += __shfl_xor(accs[c], off, 64);
    }
    if (lane < CC) {
        const int c = lane;
        const int same = (labels[b * NN + n] == c) ? 1 : 0;
        const float num = accs[c] - (same ? selfdot : 0.f);
        const float den = counts[b * CC + c] - (float)same;
        out[((size_t)b * NN + n) * CC + c] = num / den;
    }
}

// ---------------------------------------------------------------------------
extern "C" void kernel_launch(void* const* d_in, const int* in_sizes, int n_in,
                              void* d_out, int out_size, void* d_ws, size_t ws_size,
                              hipStream_t stream)
{
    const float* emb    = (const float*)d_in[0];
    const int*   labels = (const int*)  d_in[1];
    const float* Wo1f = (const float*)d_in[9];
    const float* resW = (const float*)d_in[10];
    const float* resb = (const float*)d_in[11];
    const float* ffW1 = (const float*)d_in[12];
    const float* ffb1 = (const float*)d_in[13];
    const float* ffb2 = (const float*)d_in[15];
    float* out = (float*)d_out;

    const size_t SBE = (size_t)BB * NN * DD;   // 2,097,152 elems
    u16* BUF0 = (u16*)d_ws;          // E_bf, later X1
    u16* BUF1 = BUF0 + SBE;          // gelu(emb) bf16
    u16* BUF2 = BUF1 + SBE;          // Qh [b,h,n,32]
    u16* BUF3 = BUF2 + SBE;          // Kh, later H
    u16* BUF4 = BUF3 + SBE;          // VT [b,h,32,n]
    u16* BUF5 = BUF4 + SBE;          // attn0 out (token-major)
    u16* Wt   = BUF5 + SBE;          // 9 x [256n x 256k] bf16 transposed
    float* F      = (float*)(Wt + 9 * 65536);   // [8192x256] fp32 features
    float* tvec   = F + SBE;                    // [B,256]
    float* partial= tvec + BB * 256;            // [128 bh][8 qb][32]
    float* gsum   = partial + 128 * 8 * 32;     // [B,C,256]
    float* counts = gsum + (size_t)BB * CC * DD;

    convert_all<<<2048 + 144, 256, 0, stream>>>(
        emb, BUF0, BUF1,
        (const float*)d_in[2], (const float*)d_in[3], (const float*)d_in[4],
        (const float*)d_in[5], (const float*)d_in[6], (const float*)d_in[7],
        (const float*)d_in[8], ffW1 + 256 * 256, (const float*)d_in[14], Wt);
    // QKV0 (head-major, Q pre-scaled, V transposed)
    gemm64<0,0,0,0,1><<<dim3(128, 12), 256, 0, stream>>>(
        BUF0, Wt, Wt + 65536, Wt + 2 * 65536, BUF2, BUF3, BUF4, nullptr, nullptr, nullptr);
    attn_mfma<0><<<1024, 256, 0, stream>>>(BUF2, BUF3, BUF4, BUF5, nullptr);
    // X1 = gelu(attn0 @ Wo0)
    gemm64<1,0,0,0,0><<<dim3(128, 4), 256, 0, stream>>>(
        BUF5, Wt + 3 * 65536, nullptr, nullptr, BUF0, nullptr, nullptr, nullptr, nullptr, nullptr);
    // QKV1
    gemm64<0,0,0,0,1><<<dim3(128, 12), 256, 0, stream>>>(
        BUF0, Wt + 4 * 65536, Wt + 5 * 65536, Wt + 6 * 65536, BUF2, BUF3, BUF4, nullptr, nullptr, nullptr);
    // attn1: column sums only (mean(x2) = mean(attn1) @ Wo1, done in aggr)
    attn_mfma<1><<<1024, 256, 0, stream>>>(BUF2, BUF3, BUF4, nullptr, partial);
    aggr_kernel<<<BB, 256, 0, stream>>>(partial, Wo1f, resW, resb, ffW1, tvec);
    // H = gelu(gelu(e) @ W1btm + tvec + b1)
    gemm64<1,1,1,0,0><<<dim3(128, 4), 256, 0, stream>>>(
        BUF1, Wt + 7 * 65536, nullptr, nullptr, BUF3, nullptr, nullptr, nullptr, ffb1, tvec);
    // F = H @ W2 + b2 (fp32)
    gemm64<0,1,0,1,0><<<dim3(128, 4), 256, 0, stream>>>(
        BUF3, Wt + 8 * 65536, nullptr, nullptr, nullptr, nullptr, nullptr, F, ffb2, nullptr);
    classsum_kernel<<<dim3(BB, 4), 256, 0, stream>>>(F, labels, gsum, counts);
    out_kernel<<<dim3(128, BB), 256, 0, stream>>>(F, labels, gsum, counts, out);
}